// Round 1
// baseline (852.019 us; speedup 1.0000x reference)
//
#include <hip/hip_runtime.h>
#include <hip/hip_bf16.h>

// ModulatedConv2d: B=8, Cin=Cout=512, H=W=64, K=3, style_dim=512
// Strategy: bf16 implicit GEMM per batch: out[o][p] = sum_k W'[o][k] X[k][p],
// k = (ky,kx,c), staged per (c-slice, tap).

using Acc4  = __attribute__((ext_vector_type(4))) float;
using Frag8 = __attribute__((ext_vector_type(8))) short;   // 8 bf16 (4 VGPRs)

__device__ __forceinline__ void load_lds16(const void* g, void* l) {
  // wave-uniform LDS base; HW adds lane*16. Global src is per-lane.
  __builtin_amdgcn_global_load_lds((const __attribute__((address_space(1))) void*)g,
                                   (__attribute__((address_space(3))) void*)l, 16, 0, 0);
}

// ---------------- kernel 1: style modulation + demod -> bf16 weights ------
// wout layout: [b][tap(9)][o(512)][c(512)] bf16, c contiguous (A-frag friendly)
__global__ __launch_bounds__(256) void modulate_kernel(
    const float* __restrict__ style,   // [8][512]
    const float* __restrict__ weight,  // [512][512][3][3]
    const float* __restrict__ mod_w,   // [512][512]
    __hip_bfloat16* __restrict__ wout) {
  const int ochunk = blockIdx.x;  // 0..7 -> 64 o's each
  const int b      = blockIdx.y;  // 0..7
  __shared__ float s_lds[512];
  const int tid  = threadIdx.x;
  const int lane = tid & 63;
  const int wid  = tid >> 6;

  // phase 1: s[c] = dot(style[b], mod_w[c])   (512 dots of 512)
  const float4* st = (const float4*)(style + (size_t)b * 512);
  for (int c = wid; c < 512; c += 4) {
    const float4* mw = (const float4*)(mod_w + (size_t)c * 512);
    float sum = 0.f;
#pragma unroll
    for (int i = 0; i < 2; ++i) {
      float4 m = mw[lane + i * 64];
      float4 s = st[lane + i * 64];
      sum += m.x * s.x + m.y * s.y + m.z * s.z + m.w * s.w;
    }
#pragma unroll
    for (int off = 32; off > 0; off >>= 1) sum += __shfl_xor(sum, off, 64);
    if (lane == 0) s_lds[c] = sum;
  }
  __syncthreads();

  const float scale = 1.4731391e-2f;  // 1/sqrt(512*9)

  // phase 2: per o: demod, then write modulated bf16 weights tap-major
  for (int oi = 0; oi < 16; ++oi) {
    const int o = ochunk * 64 + oi * 4 + wid;
    const float* wrow = weight + (size_t)o * 4608;   // [c][ky][kx] contiguous
    float sum = 0.f;
    for (int e = lane; e < 4608; e += 64) {
      int c = (e * 7282) >> 16;  // e/9 for e<4608
      float v = wrow[e] * s_lds[c];
      sum += v * v;
    }
#pragma unroll
    for (int off = 32; off > 0; off >>= 1) sum += __shfl_xor(sum, off, 64);
    const float demod = rsqrtf(sum * scale * scale + 1e-8f);
    const float mult  = scale * demod;
#pragma unroll
    for (int t = 0; t < 9; ++t) {
      __hip_bfloat16* orow = wout + (((size_t)b * 9 + t) * 512 + o) * 512;
      for (int c = lane; c < 512; c += 64) {
        orow[c] = __float2bfloat16(wrow[c * 9 + t] * s_lds[c] * mult);
      }
    }
  }
}

// ---------------- kernel 2: NCHW fp32 -> NHWC bf16 ------------------------
__global__ __launch_bounds__(256) void transpose_kernel(
    const float* __restrict__ x,        // [8][512][4096]
    __hip_bfloat16* __restrict__ xbf) { // [8][4096][512]
  __shared__ float t_lds[64][65];
  const int pt = blockIdx.x;   // 0..63
  const int ct = blockIdx.y;   // 0..7
  const int b  = blockIdx.z;   // 0..7
  const int tid  = threadIdx.x;
  const int lane = tid & 63;
  const int row4 = tid >> 6;   // 0..3
  const int c0 = ct * 64, p0 = pt * 64;
  const float* xb = x + ((size_t)b * 512 + c0) * 4096 + p0;
#pragma unroll
  for (int i = 0; i < 16; ++i) {
    int c = i * 4 + row4;
    t_lds[c][lane] = xb[(size_t)c * 4096 + lane];
  }
  __syncthreads();
  __hip_bfloat16* ob = xbf + ((size_t)b * 4096 + p0) * 512 + c0;
#pragma unroll
  for (int i = 0; i < 16; ++i) {
    int p = i * 4 + row4;
    ob[(size_t)p * 512 + lane] = __float2bfloat16(t_lds[lane][p]);
  }
}

// ---------------- kernel 3: implicit-GEMM conv ----------------------------
// Block: 256 thr (4 waves, 2x2), tile BM=128 (o) x BN=128 (2 image rows).
// LDS: X-tile [256 pos][64 c] (rows y0-1..y0+2) 32KB ; W-tile [128 o][64 c] 16KB.
// XOR swizzle on 16B chunks: slot(row, ch) holds global chunk (row, ch^(row&7)).
#define X_OFF 0
#define W_OFF 32768

__global__ __launch_bounds__(256, 2) void conv_kernel(
    const __hip_bfloat16* __restrict__ xbf,   // [8][4096][512]
    const __hip_bfloat16* __restrict__ wmod,  // [8][9][512][512]
    float* __restrict__ out) {                // [8][512][4096]
  __shared__ __align__(16) char lds[49152];
  const int ptile = blockIdx.x;   // 0..31  (2 rows each)
  const int otile = blockIdx.y;   // 0..3
  const int b     = blockIdx.z;   // 0..7
  const int tid  = threadIdx.x;
  const int lane = tid & 63;
  const int wid  = tid >> 6;
  const int wr   = wid >> 1, wc = wid & 1;   // wave -> 64x64 sub-tile
  const int y0   = ptile * 2;
  const int o0   = otile * 128;

  Acc4 acc[4][4] = {};
  const Frag8 zfrag = {0, 0, 0, 0, 0, 0, 0, 0};

  for (int cs = 0; cs < 8; ++cs) {
    const int c0 = cs * 64;
    __syncthreads();   // protect X tile from previous iteration's readers
    // stage X: 2048 chunks of 16B, 8 per thread
#pragma unroll
    for (int i = 0; i < 8; ++i) {
      int chunk = i * 256 + tid;
      int pos = chunk >> 3;
      int ch  = chunk & 7;
      int gy  = y0 - 1 + (pos >> 6);
      gy = min(63, max(0, gy));            // clamped rows are masked at read
      int gx  = pos & 63;
      int sch = ch ^ (pos & 7);            // pre-swizzled source chunk
      const __hip_bfloat16* src =
          xbf + (((size_t)b * 4096 + gy * 64 + gx) * 512 + c0 + sch * 8);
      load_lds16(src, lds + X_OFF + i * 4096 + wid * 1024);
    }
#pragma unroll
    for (int tap = 0; tap < 9; ++tap) {
      const int ky = tap / 3;
      const int kx = tap % 3;
      __syncthreads();   // protect W tile from previous tap's readers
      // stage W tap: 1024 chunks of 16B, 4 per thread
#pragma unroll
      for (int i = 0; i < 4; ++i) {
        int chunk = i * 256 + tid;
        int o   = chunk >> 3;
        int ch  = chunk & 7;
        int sch = ch ^ (o & 7);
        const __hip_bfloat16* src =
            wmod + ((((size_t)b * 9 + tap) * 512 + o0 + o) * 512 + c0 + sch * 8);
        load_lds16(src, lds + W_OFF + i * 4096 + wid * 1024);
      }
      __syncthreads();   // W (and X on tap 0) ready

      // per-n-frag staged position + validity (shared by both k-steps)
      int  psv[4];
      bool valid[4];
#pragma unroll
      for (int n = 0; n < 4; ++n) {
        int plocal = wc * 64 + n * 16 + (lane & 15);
        int yrel = plocal >> 6;
        int xx   = plocal & 63;
        int sx   = xx + kx - 1;
        int sy   = y0 + yrel + ky - 1;
        valid[n] = ((unsigned)sx < 64u) && ((unsigned)sy < 64u);
        psv[n]   = (((yrel + ky) * 64 + sx) & 255);
      }
#pragma unroll
      for (int ks = 0; ks < 2; ++ks) {
        Frag8 af[4], bfr[4];
        const int chq = ks * 4 + (lane >> 4);
#pragma unroll
        for (int m = 0; m < 4; ++m) {
          int o = wr * 64 + m * 16 + (lane & 15);
          af[m] = *(const Frag8*)(lds + W_OFF + o * 128 + ((chq ^ (o & 7)) << 4));
        }
#pragma unroll
        for (int n = 0; n < 4; ++n) {
          int ps = psv[n];
          Frag8 v = *(const Frag8*)(lds + X_OFF + ps * 128 + ((chq ^ (ps & 7)) << 4));
          bfr[n] = valid[n] ? v : zfrag;
        }
#pragma unroll
        for (int m = 0; m < 4; ++m)
#pragma unroll
          for (int n = 0; n < 4; ++n)
            acc[m][n] = __builtin_amdgcn_mfma_f32_16x16x32_bf16(af[m], bfr[n], acc[m][n], 0, 0, 0);
      }
    }
  }

  // epilogue: D layout col=lane&15 (p), row=(lane>>4)*4+j (o)
#pragma unroll
  for (int m = 0; m < 4; ++m) {
    int o = o0 + wr * 64 + m * 16 + ((lane >> 4) << 2);
#pragma unroll
    for (int n = 0; n < 4; ++n) {
      int p = ptile * 128 + wc * 64 + n * 16 + (lane & 15);
      float* dst = out + ((size_t)b * 512 + o) * 4096 + p;
#pragma unroll
      for (int j = 0; j < 4; ++j) dst[(size_t)j * 4096] = acc[m][n][j];
    }
  }
}

// ---------------- launch --------------------------------------------------
extern "C" void kernel_launch(void* const* d_in, const int* in_sizes, int n_in,
                              void* d_out, int out_size, void* d_ws, size_t ws_size,
                              hipStream_t stream) {
  const float* x      = (const float*)d_in[0];
  const float* style  = (const float*)d_in[1];
  const float* weight = (const float*)d_in[2];
  const float* mod_w  = (const float*)d_in[3];
  float* out = (float*)d_out;

  __hip_bfloat16* xbf  = (__hip_bfloat16*)d_ws;                       // 33.55 MB
  __hip_bfloat16* wmod = (__hip_bfloat16*)((char*)d_ws + (size_t)8 * 4096 * 512 * 2);  // 37.75 MB

  modulate_kernel<<<dim3(8, 8), 256, 0, stream>>>(style, weight, mod_w, wmod);
  transpose_kernel<<<dim3(64, 8, 8), 256, 0, stream>>>(x, xbf);
  conv_kernel<<<dim3(32, 4, 8), 256, 0, stream>>>(xbf, wmod, out);
}

// Round 2
// 282.956 us; speedup vs baseline: 3.0111x; 3.0111x over previous
//
#include <hip/hip_runtime.h>
#include <hip/hip_bf16.h>

// ModulatedConv2d: B=8, Cin=Cout=512, H=W=64, K=3, style_dim=512
// bf16 implicit GEMM per batch: out[o][p] = sum_k W'[o][k] X[k][p].

using Acc4  = __attribute__((ext_vector_type(4))) float;
using Frag8 = __attribute__((ext_vector_type(8))) short;   // 8 bf16 (4 VGPRs)

__device__ __forceinline__ void load_lds16(const void* g, void* l) {
  __builtin_amdgcn_global_load_lds((const __attribute__((address_space(1))) void*)g,
                                   (__attribute__((address_space(3))) void*)l, 16, 0, 0);
}

// ---------------- kernel 1a: s[b][c] = dot(style[b], mod_w[c]) ------------
__global__ __launch_bounds__(256) void style_kernel(
    const float* __restrict__ style,   // [8][512]
    const float* __restrict__ mod_w,   // [512][512]
    float* __restrict__ s_out) {       // [8][512]
  const int b    = blockIdx.y;
  const int wid  = threadIdx.x >> 6;
  const int lane = threadIdx.x & 63;
  const int c    = blockIdx.x * 4 + wid;
  const float4* mw = (const float4*)(mod_w + (size_t)c * 512);
  const float4* st = (const float4*)(style + (size_t)b * 512);
  float sum = 0.f;
#pragma unroll
  for (int i = 0; i < 2; ++i) {
    float4 m = mw[lane + i * 64];
    float4 s = st[lane + i * 64];
    sum += m.x * s.x + m.y * s.y + m.z * s.z + m.w * s.w;
  }
#pragma unroll
  for (int off = 32; off > 0; off >>= 1) sum += __shfl_xor(sum, off, 64);
  if (lane == 0) s_out[b * 512 + c] = sum;
}

// ---------------- kernel 1b: demod + modulated bf16 weight write ----------
// One block per (o, b). wout layout: [b][tap(9)][o(512)][c(512)] bf16.
__global__ __launch_bounds__(256) void modwrite_kernel(
    const float* __restrict__ weight,  // [512][512][3][3] ([o][c][ky][kx])
    const float* __restrict__ s_in,    // [8][512]
    __hip_bfloat16* __restrict__ wout) {
  const int o = blockIdx.x;
  const int b = blockIdx.y;
  __shared__ float ws[4608];
  __shared__ float s_lds[512];
  __shared__ float red[4];
  __shared__ float s_mult;
  const int tid  = threadIdx.x;
  const int lane = tid & 63;
  const int wid  = tid >> 6;

  for (int i = tid; i < 512; i += 256) s_lds[i] = s_in[b * 512 + i];
  __syncthreads();

  const float2* w2 = (const float2*)(weight + (size_t)o * 4608);
  float sum = 0.f;
#pragma unroll
  for (int i = 0; i < 9; ++i) {
    int idx = i * 256 + tid;          // float2 index 0..2303
    float2 v = w2[idx];
    int e0 = idx * 2;
    int c0 = (e0 * 7282) >> 16;       // e/9 for e<4608
    int c1 = ((e0 + 1) * 7282) >> 16;
    float a  = v.x * s_lds[c0];
    float bb = v.y * s_lds[c1];
    ws[e0] = a; ws[e0 + 1] = bb;
    sum += a * a + bb * bb;
  }
#pragma unroll
  for (int off = 32; off > 0; off >>= 1) sum += __shfl_xor(sum, off, 64);
  if (lane == 0) red[wid] = sum;
  __syncthreads();
  if (tid == 0) {
    const float scale = 1.4731391e-2f;  // 1/sqrt(512*9)
    float t = red[0] + red[1] + red[2] + red[3];
    s_mult = scale * rsqrtf(t * scale * scale + 1e-8f);
  }
  __syncthreads();
  const float mult = s_mult;
#pragma unroll
  for (int t = 0; t < 9; ++t) {
    __hip_bfloat16* orow = wout + (((size_t)b * 9 + t) * 512 + o) * 512;
#pragma unroll
    for (int i = 0; i < 2; ++i) {
      int c = i * 256 + tid;
      orow[c] = __float2bfloat16(ws[c * 9 + t] * mult);  // stride-9: conflict-free
    }
  }
}

// ---------------- kernel 2: NCHW fp32 -> NHWC bf16 ------------------------
__global__ __launch_bounds__(256) void transpose_kernel(
    const float* __restrict__ x,        // [8][512][4096]
    __hip_bfloat16* __restrict__ xbf) { // [8][4096][512]
  __shared__ float t_lds[64][65];
  const int pt = blockIdx.x;   // 0..63
  const int ct = blockIdx.y;   // 0..7
  const int b  = blockIdx.z;   // 0..7
  const int tid  = threadIdx.x;
  const int lane = tid & 63;
  const int row4 = tid >> 6;   // 0..3
  const int c0 = ct * 64, p0 = pt * 64;
  const float* xb = x + ((size_t)b * 512 + c0) * 4096 + p0;
#pragma unroll
  for (int i = 0; i < 16; ++i) {
    int c = i * 4 + row4;
    t_lds[c][lane] = xb[(size_t)c * 4096 + lane];
  }
  __syncthreads();
  __hip_bfloat16* ob = xbf + ((size_t)b * 4096 + p0) * 512 + c0;
#pragma unroll
  for (int i = 0; i < 16; ++i) {
    int p = i * 4 + row4;
    ob[(size_t)p * 512 + lane] = __float2bfloat16(t_lds[lane][p]);
  }
}

// ---------------- kernel 3: implicit-GEMM conv ----------------------------
// Block: 256 thr (4 waves, 2x2), tile BM=128 (o) x BN=128 (2 image rows).
// LDS: X-tile [256 pos][64 c] 32KB ; W-tile [128 o][64 c] 16KB.
// XOR swizzle on 16B chunks: slot(row, ch) holds global chunk (row, ch^(row&7)).
#define X_OFF 0
#define W_OFF 32768

__global__ __launch_bounds__(256, 2) void conv_kernel(
    const __hip_bfloat16* __restrict__ xbf,   // [8][4096][512]
    const __hip_bfloat16* __restrict__ wmod,  // [8][9][512][512]
    float* __restrict__ out) {                // [8][512][4096]
  __shared__ __align__(16) char lds[49152];
  const int ptile = blockIdx.x;   // 0..31  (2 rows each)
  const int otile = blockIdx.y;   // 0..3
  const int b     = blockIdx.z;   // 0..7
  const int tid  = threadIdx.x;
  const int lane = tid & 63;
  const int wid  = tid >> 6;
  const int wr   = wid >> 1, wc = wid & 1;
  const int y0   = ptile * 2;
  const int o0   = otile * 128;

  Acc4 acc[4][4] = {};
  const Frag8 zfrag = {0, 0, 0, 0, 0, 0, 0, 0};

  for (int cs = 0; cs < 8; ++cs) {
    const int c0 = cs * 64;
    __syncthreads();
#pragma unroll
    for (int i = 0; i < 8; ++i) {
      int chunk = i * 256 + tid;
      int pos = chunk >> 3;
      int ch  = chunk & 7;
      int gy  = y0 - 1 + (pos >> 6);
      gy = min(63, max(0, gy));
      int gx  = pos & 63;
      int sch = ch ^ (pos & 7);
      const __hip_bfloat16* src =
          xbf + (((size_t)b * 4096 + gy * 64 + gx) * 512 + c0 + sch * 8);
      load_lds16(src, lds + X_OFF + i * 4096 + wid * 1024);
    }
#pragma unroll
    for (int tap = 0; tap < 9; ++tap) {
      const int ky = tap / 3;
      const int kx = tap % 3;
      __syncthreads();
#pragma unroll
      for (int i = 0; i < 4; ++i) {
        int chunk = i * 256 + tid;
        int o   = chunk >> 3;
        int ch  = chunk & 7;
        int sch = ch ^ (o & 7);
        const __hip_bfloat16* src =
            wmod + ((((size_t)b * 9 + tap) * 512 + o0 + o) * 512 + c0 + sch * 8);
        load_lds16(src, lds + W_OFF + i * 4096 + wid * 1024);
      }
      __syncthreads();

      int  psv[4];
      bool valid[4];
#pragma unroll
      for (int n = 0; n < 4; ++n) {
        int plocal = wc * 64 + n * 16 + (lane & 15);
        int yrel = plocal >> 6;
        int xx   = plocal & 63;
        int sx   = xx + kx - 1;
        int sy   = y0 + yrel + ky - 1;
        valid[n] = ((unsigned)sx < 64u) && ((unsigned)sy < 64u);
        psv[n]   = (((yrel + ky) * 64 + sx) & 255);
      }
#pragma unroll
      for (int ks = 0; ks < 2; ++ks) {
        Frag8 af[4], bfr[4];
        const int chq = ks * 4 + (lane >> 4);
#pragma unroll
        for (int m = 0; m < 4; ++m) {
          int o = wr * 64 + m * 16 + (lane & 15);
          af[m] = *(const Frag8*)(lds + W_OFF + o * 128 + ((chq ^ (o & 7)) << 4));
        }
#pragma unroll
        for (int n = 0; n < 4; ++n) {
          int ps = psv[n];
          Frag8 v = *(const Frag8*)(lds + X_OFF + ps * 128 + ((chq ^ (ps & 7)) << 4));
          bfr[n] = valid[n] ? v : zfrag;
        }
#pragma unroll
        for (int m = 0; m < 4; ++m)
#pragma unroll
          for (int n = 0; n < 4; ++n)
            acc[m][n] = __builtin_amdgcn_mfma_f32_16x16x32_bf16(af[m], bfr[n], acc[m][n], 0, 0, 0);
      }
    }
  }

#pragma unroll
  for (int m = 0; m < 4; ++m) {
    int o = o0 + wr * 64 + m * 16 + ((lane >> 4) << 2);
#pragma unroll
    for (int n = 0; n < 4; ++n) {
      int p = ptile * 128 + wc * 64 + n * 16 + (lane & 15);
      float* dst = out + ((size_t)b * 512 + o) * 4096 + p;
#pragma unroll
      for (int j = 0; j < 4; ++j) dst[(size_t)j * 4096] = acc[m][n][j];
    }
  }
}

// ---------------- launch --------------------------------------------------
extern "C" void kernel_launch(void* const* d_in, const int* in_sizes, int n_in,
                              void* d_out, int out_size, void* d_ws, size_t ws_size,
                              hipStream_t stream) {
  const float* x      = (const float*)d_in[0];
  const float* style  = (const float*)d_in[1];
  const float* weight = (const float*)d_in[2];
  const float* mod_w  = (const float*)d_in[3];
  float* out = (float*)d_out;

  __hip_bfloat16* xbf  = (__hip_bfloat16*)d_ws;                       // 33.55 MB
  __hip_bfloat16* wmod = (__hip_bfloat16*)((char*)d_ws + (size_t)8 * 4096 * 512 * 2);
  // s[8][512] lives in the first 16KB of the xbf region; it is fully consumed
  // by modwrite_kernel BEFORE transpose_kernel overwrites it (stream order).
  float* s_buf = (float*)d_ws;

  style_kernel   <<<dim3(128, 8), 256, 0, stream>>>(style, mod_w, s_buf);
  modwrite_kernel<<<dim3(512, 8), 256, 0, stream>>>(weight, s_buf, wmod);
  transpose_kernel<<<dim3(64, 8, 8), 256, 0, stream>>>(x, xbf);
  conv_kernel    <<<dim3(32, 4, 8), 256, 0, stream>>>(xbf, wmod, out);
}

// Round 3
// 256.685 us; speedup vs baseline: 3.3193x; 1.1023x over previous
//
#include <hip/hip_runtime.h>
#include <hip/hip_bf16.h>

// ModulatedConv2d: B=8, Cin=Cout=512, H=W=64, K=3, style_dim=512
// bf16 implicit GEMM per batch: out[o][p] = sum_k W'[o][k] X[k][p].

using Acc4  = __attribute__((ext_vector_type(4))) float;
using Frag8 = __attribute__((ext_vector_type(8))) short;   // 8 bf16 (4 VGPRs)

__device__ __forceinline__ void load_lds16(const void* g, void* l) {
  __builtin_amdgcn_global_load_lds((const __attribute__((address_space(1))) void*)g,
                                   (__attribute__((address_space(3))) void*)l, 16, 0, 0);
}

// ---------------- kernel 1a: s[b][c] = dot(style[b], mod_w[c]) ------------
__global__ __launch_bounds__(256) void style_kernel(
    const float* __restrict__ style,   // [8][512]
    const float* __restrict__ mod_w,   // [512][512]
    float* __restrict__ s_out) {       // [8][512]
  const int b    = blockIdx.y;
  const int wid  = threadIdx.x >> 6;
  const int lane = threadIdx.x & 63;
  const int c    = blockIdx.x * 4 + wid;
  const float4* mw = (const float4*)(mod_w + (size_t)c * 512);
  const float4* st = (const float4*)(style + (size_t)b * 512);
  float sum = 0.f;
#pragma unroll
  for (int i = 0; i < 2; ++i) {
    float4 m = mw[lane + i * 64];
    float4 s = st[lane + i * 64];
    sum += m.x * s.x + m.y * s.y + m.z * s.z + m.w * s.w;
  }
#pragma unroll
  for (int off = 32; off > 0; off >>= 1) sum += __shfl_xor(sum, off, 64);
  if (lane == 0) s_out[b * 512 + c] = sum;
}

// ---------------- kernel 1b: demod + modulated bf16 weight write ----------
// One block per (o, b). wout layout: [b][tap(9)][o(512)][c(512)] bf16.
__global__ __launch_bounds__(256) void modwrite_kernel(
    const float* __restrict__ weight,  // [512][512][3][3] ([o][c][ky][kx])
    const float* __restrict__ s_in,    // [8][512]
    __hip_bfloat16* __restrict__ wout) {
  const int o = blockIdx.x;
  const int b = blockIdx.y;
  __shared__ float ws[4608];
  __shared__ float s_lds[512];
  __shared__ float red[4];
  __shared__ float s_mult;
  const int tid  = threadIdx.x;
  const int lane = tid & 63;
  const int wid  = tid >> 6;

  for (int i = tid; i < 512; i += 256) s_lds[i] = s_in[b * 512 + i];
  __syncthreads();

  const float2* w2 = (const float2*)(weight + (size_t)o * 4608);
  float sum = 0.f;
#pragma unroll
  for (int i = 0; i < 9; ++i) {
    int idx = i * 256 + tid;          // float2 index 0..2303
    float2 v = w2[idx];
    int e0 = idx * 2;
    int c0 = (e0 * 7282) >> 16;       // e/9 for e<4608
    int c1 = ((e0 + 1) * 7282) >> 16;
    float a  = v.x * s_lds[c0];
    float bb = v.y * s_lds[c1];
    ws[e0] = a; ws[e0 + 1] = bb;
    sum += a * a + bb * bb;
  }
#pragma unroll
  for (int off = 32; off > 0; off >>= 1) sum += __shfl_xor(sum, off, 64);
  if (lane == 0) red[wid] = sum;
  __syncthreads();
  if (tid == 0) {
    const float scale = 1.4731391e-2f;  // 1/sqrt(512*9)
    float t = red[0] + red[1] + red[2] + red[3];
    s_mult = scale * rsqrtf(t * scale * scale + 1e-8f);
  }
  __syncthreads();
  const float mult = s_mult;
  const int c = tid * 2;
#pragma unroll
  for (int t = 0; t < 9; ++t) {
    __hip_bfloat16* orow = wout + (((size_t)b * 9 + t) * 512 + o) * 512;
    __hip_bfloat16 h0 = __float2bfloat16(ws[c * 9 + t] * mult);
    __hip_bfloat16 h1 = __float2bfloat16(ws[(c + 1) * 9 + t] * mult);
    ushort2 pk = { *(unsigned short*)&h0, *(unsigned short*)&h1 };
    *(ushort2*)(orow + c) = pk;       // 4B/lane coalesced
  }
}

// ---------------- kernel 2: NCHW fp32 -> NHWC bf16 ------------------------
__global__ __launch_bounds__(256) void transpose_kernel(
    const float* __restrict__ x,        // [8][512][4096]
    __hip_bfloat16* __restrict__ xbf) { // [8][4096][512]
  __shared__ float t_lds[64][65];
  const int pt = blockIdx.x;   // 0..63
  const int ct = blockIdx.y;   // 0..7
  const int b  = blockIdx.z;   // 0..7
  const int tid = threadIdx.x;
  const int l16 = tid & 15, g16 = tid >> 4;
  const int c0 = ct * 64, p0 = pt * 64;
  const float* xb = x + ((size_t)b * 512 + c0) * 4096 + p0;
#pragma unroll
  for (int i = 0; i < 4; ++i) {
    int c = i * 16 + g16;
    float4 v = *(const float4*)(xb + (size_t)c * 4096 + l16 * 4);
    t_lds[c][l16 * 4 + 0] = v.x; t_lds[c][l16 * 4 + 1] = v.y;
    t_lds[c][l16 * 4 + 2] = v.z; t_lds[c][l16 * 4 + 3] = v.w;
  }
  __syncthreads();
  __hip_bfloat16* ob = xbf + ((size_t)b * 4096 + p0) * 512 + c0;
#pragma unroll
  for (int i = 0; i < 4; ++i) {
    int p = i * 16 + g16;
    int c = l16 * 4;
    __hip_bfloat16 h0 = __float2bfloat16(t_lds[c + 0][p]);
    __hip_bfloat16 h1 = __float2bfloat16(t_lds[c + 1][p]);
    __hip_bfloat16 h2 = __float2bfloat16(t_lds[c + 2][p]);
    __hip_bfloat16 h3 = __float2bfloat16(t_lds[c + 3][p]);
    ushort4 pk = { *(unsigned short*)&h0, *(unsigned short*)&h1,
                   *(unsigned short*)&h2, *(unsigned short*)&h3 };
    *(ushort4*)(ob + (size_t)p * 512 + c) = pk;   // 8B/lane coalesced
  }
}

// ---------------- kernel 3: implicit-GEMM conv, W double-buffered ---------
// Block: 256 thr (4 waves, 2x2), tile BM=128 (o) x BN=128 (2 image rows).
// LDS: X [256 pos][64 c] 32KB at 0 ; W[2] [128 o][64 c] 16KB at 32K/48K.
// Per-tap pipeline: issue next-W stage -> compute cur tap -> vmcnt(0)+barrier.
// XOR swizzle on 16B chunks: slot(row, ch) holds global chunk (row, ch^(row&7)).
#define X_OFF 0
#define W_OFF 32768

__global__ __launch_bounds__(256, 2) void conv_kernel(
    const __hip_bfloat16* __restrict__ xbf,   // [8][4096][512]
    const __hip_bfloat16* __restrict__ wmod,  // [8][9][512][512]
    float* __restrict__ out) {                // [8][512][4096]
  __shared__ __align__(16) char lds[65536];
  // XCD swizzle: 1024 blocks, 8 XCDs round-robin on blockIdx.x -> XCD x owns
  // nid in [x*128, x*128+128) == the ENTIRE batch sample b=x (all otile/ptile).
  const int bid  = blockIdx.x;
  const int nid  = (bid & 7) * 128 + (bid >> 3);
  const int ptile = nid & 31;
  const int otile = (nid >> 5) & 3;
  const int b     = nid >> 7;
  const int tid  = threadIdx.x;
  const int lane = tid & 63;
  const int wid  = tid >> 6;
  const int wr   = wid >> 1, wc = wid & 1;
  const int y0   = ptile * 2;
  const int o0   = otile * 128;

  Acc4 acc[4][4] = {};
  const Frag8 zfrag = {0, 0, 0, 0, 0, 0, 0, 0};

  auto stageX = [&](int cs) {
    const int c0 = cs * 64;
#pragma unroll
    for (int i = 0; i < 8; ++i) {
      int chunk = i * 256 + tid;
      int pos = chunk >> 3, ch = chunk & 7;
      int gy  = min(63, max(0, y0 - 1 + (pos >> 6)));
      int gx  = pos & 63;
      int sch = ch ^ (pos & 7);
      load_lds16(xbf + (((size_t)b * 4096 + gy * 64 + gx) * 512 + c0 + sch * 8),
                 lds + X_OFF + i * 4096 + wid * 1024);
    }
  };
  auto stageW = [&](int cs, int tap, int dst) {
    const int c0 = cs * 64;
#pragma unroll
    for (int i = 0; i < 4; ++i) {
      int chunk = i * 256 + tid;
      int o = chunk >> 3, ch = chunk & 7;
      int sch = ch ^ (o & 7);
      load_lds16(wmod + ((((size_t)b * 9 + tap) * 512 + o0 + o) * 512 + c0 + sch * 8),
                 lds + dst + i * 4096 + wid * 1024);
    }
  };

  int woff = W_OFF;
  stageX(0);
  stageW(0, 0, woff);
  asm volatile("s_waitcnt vmcnt(0)" ::: "memory");
  __builtin_amdgcn_s_barrier();

  for (int cs = 0; cs < 8; ++cs) {
#pragma unroll
    for (int tap = 0; tap < 9; ++tap) {
      // 1. issue next W-tap stage into the other buffer (its last readers
      //    finished before the barrier that ended the previous tap)
      if (tap < 8)           stageW(cs, tap + 1, woff ^ 16384);
      else if (cs < 7)       stageW(cs + 1, 0, woff ^ 16384);

      // 2. compute current tap from W[woff] + X
      const int ky = tap / 3;
      const int kx = tap % 3;
      int  psv[4];
      bool valid[4];
#pragma unroll
      for (int n = 0; n < 4; ++n) {
        int plocal = wc * 64 + n * 16 + (lane & 15);
        int yrel = plocal >> 6;
        int xx   = plocal & 63;
        int sx   = xx + kx - 1;
        int sy   = y0 + yrel + ky - 1;
        valid[n] = ((unsigned)sx < 64u) && ((unsigned)sy < 64u);
        psv[n]   = (((yrel + ky) * 64 + sx) & 255);
      }
#pragma unroll
      for (int ks = 0; ks < 2; ++ks) {
        Frag8 af[4], bfr[4];
        const int chq = ks * 4 + (lane >> 4);
#pragma unroll
        for (int m = 0; m < 4; ++m) {
          int o = wr * 64 + m * 16 + (lane & 15);
          af[m] = *(const Frag8*)(lds + woff + o * 128 + ((chq ^ (o & 7)) << 4));
        }
#pragma unroll
        for (int n = 0; n < 4; ++n) {
          int ps = psv[n];
          Frag8 v = *(const Frag8*)(lds + X_OFF + ps * 128 + ((chq ^ (ps & 7)) << 4));
          bfr[n] = valid[n] ? v : zfrag;
        }
#pragma unroll
        for (int m = 0; m < 4; ++m)
#pragma unroll
          for (int n = 0; n < 4; ++n)
            acc[m][n] = __builtin_amdgcn_mfma_f32_16x16x32_bf16(af[m], bfr[n], acc[m][n], 0, 0, 0);
      }

      // 3. end-of-tap sync
      if (tap < 8) {
        asm volatile("s_waitcnt vmcnt(0)" ::: "memory");
        __builtin_amdgcn_s_barrier();
      } else {
        __builtin_amdgcn_s_barrier();          // all waves done reading X[cs]
        if (cs < 7) stageX(cs + 1);
        asm volatile("s_waitcnt vmcnt(0)" ::: "memory");
        __builtin_amdgcn_s_barrier();
      }
      woff ^= 16384;
    }
  }

  // epilogue: D layout col=lane&15 (p), row=(lane>>4)*4+j (o)
#pragma unroll
  for (int m = 0; m < 4; ++m) {
    int o = o0 + wr * 64 + m * 16 + ((lane >> 4) << 2);
#pragma unroll
    for (int n = 0; n < 4; ++n) {
      int p = ptile * 128 + wc * 64 + n * 16 + (lane & 15);
      float* dst = out + ((size_t)b * 512 + o) * 4096 + p;
#pragma unroll
      for (int j = 0; j < 4; ++j) dst[(size_t)j * 4096] = acc[m][n][j];
    }
  }
}

// ---------------- launch --------------------------------------------------
extern "C" void kernel_launch(void* const* d_in, const int* in_sizes, int n_in,
                              void* d_out, int out_size, void* d_ws, size_t ws_size,
                              hipStream_t stream) {
  const float* x      = (const float*)d_in[0];
  const float* style  = (const float*)d_in[1];
  const float* weight = (const float*)d_in[2];
  const float* mod_w  = (const float*)d_in[3];
  float* out = (float*)d_out;

  __hip_bfloat16* xbf  = (__hip_bfloat16*)d_ws;                       // 33.55 MB
  __hip_bfloat16* wmod = (__hip_bfloat16*)((char*)d_ws + (size_t)8 * 4096 * 512 * 2);
  // s[8][512] lives in the first 16KB of the xbf region; fully consumed by
  // modwrite_kernel BEFORE transpose_kernel overwrites it (stream order).
  float* s_buf = (float*)d_ws;

  style_kernel    <<<dim3(128, 8), 256, 0, stream>>>(style, mod_w, s_buf);
  modwrite_kernel <<<dim3(512, 8), 256, 0, stream>>>(weight, s_buf, wmod);
  transpose_kernel<<<dim3(64, 8, 8), 256, 0, stream>>>(x, xbf);
  conv_kernel     <<<dim3(1024), 256, 0, stream>>>(xbf, wmod, out);
}